// Round 5
// baseline (684.179 us; speedup 1.0000x reference)
//
#include <hip/hip_runtime.h>
#include <math.h>
#include <string.h>

#define NLAT 91
#define NLON 180
#define NCH  64
#define KSZ  25
#define NW   9
#define HALF 4
#define NB   2
#define CG   8
#define CPG  8      // NCH / CG
#define THREADS 192
#define XW   360    // doubled row width
#define XSPAD 8
#define QUNIT 160   // quads per balanced work unit
#define QCAP 32768
#define UCAP 2048
#define LCAP 1024

// blob layout (all 256-aligned)
#define KOFF_OFF   0
#define UNITS_OFF  9728                         // after 91*26*4 = 9464
#define QVALS_OFF  (UNITS_OFF + UCAP * 16)      // 42496 (16B aligned)
#define QBASE_OFF  (QVALS_OFF + QCAP * 16)      // 566784
#define BLOB_MAX   (QBASE_OFF + QCAP * 4)       // 697856

#ifndef M_PI
#define M_PI 3.14159265358979323846
#endif

typedef unsigned int u32;

// ---------------------------------------------------------------------------
// HOST: build RLE-quad DISCO tables bit-compatibly with the numpy reference
// (glibc libm, exact IEEE op order, contraction off). Per (t,k): entries
// sorted by LDS offset; consecutive runs chopped into quads {base, 4 psi},
// tail quads overlap the run with zeroed duplicates (no overcount, no
// out-of-window reads beyond +3).
// ---------------------------------------------------------------------------
static int build_tables(unsigned char* blob, int* nq_out)
{
#pragma clang fp contract(off)
    int*   koff  = (int*)(blob + KOFF_OFF);
    u32*   units = (u32*)(blob + UNITS_OFF);
    float* qvals = (float*)(blob + QVALS_OFF);
    u32*   qbase = (u32*)(blob + QBASE_OFF);

    static double sth[NLAT], cth[NLAT], cphv[NLON], sphv[NLON];
    for (int t = 0; t < NLAT; t++) {
        double th = (M_PI * (double)t) / 90.0;
        sth[t] = sin(th); cth[t] = cos(th);
    }
    for (int q = 0; q < NLON; q++) {
        double ph = (2.0 * M_PI * (double)q) / 180.0;
        cphv[q] = cos(ph); sphv[q] = sin(ph);
    }
    const double cutoff = (4.0 * M_PI) / 90.0;
    const double dr     = cutoff / 4.0;         // NR-1 = 4
    const double dphi   = (2.0 * M_PI) / 6.0;   // NPHI = 6

    static int   lcnt[KSZ];
    static int   loff_[KSZ][LCAP];
    static float lval[KSZ][LCAP];

    int nq = 0, nu = 0;
    for (int t = 0; t < NLAT; t++) {
        for (int k = 0; k < KSZ; k++) lcnt[k] = 0;
        for (int w = 0; w < NW; w++) {
            int ti_raw = t - HALF + w;
            int valid = (ti_raw >= 0) && (ti_raw < NLAT);
            int ti = ti_raw < 0 ? 0 : (ti_raw > NLAT - 1 ? NLAT - 1 : ti_raw);
            for (int dq = -89; dq <= 90; dq++) {     // offset-ascending order
                int q = dq < 0 ? dq + NLON : dq;
                double t1 = sth[t] * sth[ti];
                double t2 = t1 * cphv[q];
                double t3 = cth[t] * cth[ti];
                double zz = t2 + t3;
                if (zz > 1.0) zz = 1.0;
                if (zz < -1.0) zz = -1.0;
                double r = acos(zz);
                if (!(valid && (r <= cutoff))) continue;
                double xx = (cth[t] * sth[ti]) * cphv[q] - sth[t] * cth[ti];
                double yy = sth[ti] * sphv[q];
                double phi = atan2(yy, xx);
                { double m = fmod(phi, 2.0 * M_PI); if (m < 0.0) m += 2.0 * M_PI; phi = m; }
                double quad = sth[ti] * (M_PI / 90.0) * ((2.0 * M_PI) / 180.0);
                int off = w * XW + 90 + dq;
                double v0 = fmax(0.0, 1.0 - r / dr);
                float f0 = (float)(v0 * quad);
                if (f0 != 0.f && lcnt[0] < LCAP) {
                    loff_[0][lcnt[0]] = off; lval[0][lcnt[0]] = f0; lcnt[0]++;
                }
                for (int ir = 1; ir < 5; ir++) {
                    double rad = fmax(0.0, 1.0 - fabs(r - ir * dr) / dr);
                    for (int ip = 0; ip < 6; ip++) {
                        double a = (phi - ip * dphi) + M_PI;
                        double m = fmod(a, 2.0 * M_PI);
                        if (m < 0.0) m += 2.0 * M_PI;
                        double dp = fabs(m - M_PI);
                        double ang = fmax(0.0, 1.0 - dp / dphi);
                        float f = (float)((rad * ang) * quad);
                        int k = 1 + (ir - 1) * 6 + ip;
                        if (f != 0.f && lcnt[k] < LCAP) {
                            loff_[k][lcnt[k]] = off; lval[k][lcnt[k]] = f; lcnt[k]++;
                        }
                    }
                }
            }
        }
        int tQ = nq;
        for (int k = 0; k < KSZ; k++) {
            koff[t * (KSZ + 1) + k] = nq;
            int i = 0;
            while (i < lcnt[k] && nq < QCAP) {
                int j = i;
                while (j + 1 < lcnt[k] && loff_[k][j + 1] == loff_[k][j] + 1) j++;
                int L = j - i + 1;
                int full = L / 4, rem = L - 4 * full;
                for (int f = 0; f < full && nq < QCAP; f++) {
                    qbase[nq] = (u32)loff_[k][i + 4 * f];
                    for (int s = 0; s < 4; s++) qvals[4 * nq + s] = lval[k][i + 4 * f + s];
                    nq++;
                }
                if (rem && nq < QCAP) {
                    if (L >= 4) {           // overlap tail: zero the re-covered slots
                        qbase[nq] = (u32)(loff_[k][i] + L - 4);
                        for (int s = 0; s < 4; s++)
                            qvals[4 * nq + s] = (s >= 4 - rem) ? lval[k][i + L - 4 + s] : 0.f;
                    } else {                // short run: pad tail with zeros
                        qbase[nq] = (u32)loff_[k][i];
                        for (int s = 0; s < 4; s++)
                            qvals[4 * nq + s] = (s < rem) ? lval[k][i + s] : 0.f;
                    }
                    nq++;
                }
                i = j + 1;
            }
        }
        koff[t * (KSZ + 1) + KSZ] = nq;
        for (int q0 = tQ; q0 < nq; q0 += QUNIT) {
            int q1 = q0 + QUNIT < nq ? q0 + QUNIT : nq;
            int kb = 0;
            while (kb < KSZ &&
                   !(koff[t * (KSZ + 1) + kb] <= q0 && q0 < koff[t * (KSZ + 1) + kb + 1]))
                kb++;
            if (nu < UCAP) {
                units[nu * 4 + 0] = (u32)t;
                units[nu * 4 + 1] = (u32)q0;
                units[nu * 4 + 2] = (u32)q1;
                units[nu * 4 + 3] = (u32)kb;
                nu++;
            }
        }
    }
    *nq_out = nq;
    return nu;
}

// ---------------------------------------------------------------------------
// Kernel: transpose weights [o][c][k] -> wt[c][k][o] (contiguous o).
// ---------------------------------------------------------------------------
__global__ void transpose_w(const float* __restrict__ wgt, float* __restrict__ wt)
{
    int i = blockIdx.x * blockDim.x + threadIdx.x;
    if (i >= NCH * NCH * KSZ) return;
    int o = i / (NCH * KSZ);
    int rem = i - o * (NCH * KSZ);
    int c = rem / KSZ;
    int k = rem - c * KSZ;
    wt[((size_t)c * KSZ + k) * NCH + o] = wgt[i];
}

// ---------------------------------------------------------------------------
// Main fused kernel. Block = (unit, cg, b); thread owns longitude p.
// Unit descriptor readfirstlane'd -> all control flow + table/weight loads
// scalar (s_load); per quad: 1 addr add + 4 ds_read_b32 + 4 v_fmac with
// SGPR psi. Stage-2 flush per k: 64 v_fmac with SGPR weights.
// ---------------------------------------------------------------------------
__global__ __launch_bounds__(THREADS, 4) void disco_fused(
    const float* __restrict__ x, const float* __restrict__ wt,
    const u32* __restrict__ qbase, const float4* __restrict__ qvals,
    const int* __restrict__ koffG, const uint4* __restrict__ units,
    float* __restrict__ out)
{
    uint4 uu = units[blockIdx.x];
    int t    = __builtin_amdgcn_readfirstlane((int)uu.x);
    int qBeg = __builtin_amdgcn_readfirstlane((int)uu.y);
    int qEnd = __builtin_amdgcn_readfirstlane((int)uu.z);
    int kBeg = __builtin_amdgcn_readfirstlane((int)uu.w);
    int cg = blockIdx.y, b = blockIdx.z;
    int tid = threadIdx.x;
    int p = tid < NLON ? tid : NLON - 1;
    bool act = tid < NLON;

    __shared__ float xs[NW * XW + XSPAD];
    const int* ko = koffG + t * (KSZ + 1);

    float acc[NCH];
#pragma unroll
    for (int o = 0; o < NCH; o++) acc[o] = 0.f;

    for (int ci = 0; ci < CPG; ci++) {
        int c = cg * CPG + ci;
        __syncthreads();
        const float* xc = x + ((size_t)(b * NCH + c)) * (NLAT * NLON);
#pragma unroll
        for (int w = 0; w < NW; w++) {
            int tw = t - HALF + w;
            int ti = tw < 0 ? 0 : (tw > NLAT - 1 ? NLAT - 1 : tw);
            const float* xr = xc + ti * NLON;
            for (int i = tid; i < XW; i += THREADS) {
                int src = i + 90;
                if (src >= NLON) src -= NLON;
                if (src >= NLON) src -= NLON;
                xs[w * XW + i] = xr[src];
            }
        }
        if (tid < XSPAD) xs[NW * XW + tid] = 0.f;
        __syncthreads();

        const float* xp = xs + p;
        int e = qBeg, k = kBeg;
        while (e < qEnd) {
            int kend = ko[k + 1];
            if (kend > qEnd) kend = qEnd;
            float z0 = 0.f, z1 = 0.f, z2 = 0.f, z3 = 0.f;
            for (; e < kend; ++e) {
                int base = (int)qbase[e];      // s_load (e scalar)
                float4 pv = qvals[e];          // s_load_dwordx4
                const float* xq = xp + base;   // 1 VALU add per 4 FMAs
                z0 = fmaf(pv.x, xq[0], z0);
                z1 = fmaf(pv.y, xq[1], z1);
                z2 = fmaf(pv.z, xq[2], z2);
                z3 = fmaf(pv.w, xq[3], z3);
            }
            float zk = (z0 + z1) + (z2 + z3);
            const float* wk = wt + ((size_t)c * KSZ + k) * NCH;  // scalar addr
#pragma unroll
            for (int o = 0; o < NCH; o++)
                acc[o] = fmaf(wk[o], zk, acc[o]);
            k++;
            if (k >= KSZ) break;  // defensive (host invariant: e==qEnd here)
        }
    }

    if (act) {
        float* op = out + ((size_t)b * NCH * NLAT * NLON) + (size_t)t * NLON + p;
#pragma unroll
        for (int o = 0; o < NCH; o++)
            atomicAdd(op + (size_t)o * (NLAT * NLON), acc[o]);
    }
}

extern "C" void kernel_launch(void* const* d_in, const int* in_sizes, int n_in,
                              void* d_out, int out_size, void* d_ws, size_t ws_size,
                              hipStream_t stream)
{
    const float* x   = (const float*)d_in[0];
    const float* wgt = (const float*)d_in[1];
    char* ws = (char*)d_ws;

    const size_t WT_BYTES = (size_t)NCH * KSZ * NCH * 4;   // 409600 (256-aligned)
    float* wt = (float*)ws;
    unsigned char* d_blob = (unsigned char*)(ws + WT_BYTES);

    // Host tables: recomputed identically each call; static blob keeps the
    // pointer valid for graph replay.
    static unsigned char h_blob[BLOB_MAX];
    int nq = 0;
    int nu = build_tables(h_blob, &nq);
    size_t blob_bytes = (size_t)QBASE_OFF + (size_t)nq * 4;  // qbase is the tail

    hipMemsetAsync(d_out, 0, (size_t)out_size * 4, stream);
    hipMemcpyAsync(d_blob, h_blob, blob_bytes, hipMemcpyHostToDevice, stream);
    transpose_w<<<(NCH * NCH * KSZ + 255) / 256, 256, 0, stream>>>(wgt, wt);

    const u32*    qbaseD = (const u32*)(d_blob + QBASE_OFF);
    const float4* qvalsD = (const float4*)(d_blob + QVALS_OFF);
    const int*    koffD  = (const int*)(d_blob + KOFF_OFF);
    const uint4*  unitsD = (const uint4*)(d_blob + UNITS_OFF);

    disco_fused<<<dim3(nu, CG, NB), THREADS, 0, stream>>>(
        x, wt, qbaseD, qvalsD, koffD, unitsD, (float*)d_out);
}